// Round 9
// baseline (288.982 us; speedup 1.0000x reference)
//
#include <hip/hip_runtime.h>
#include <stdint.h>

typedef __bf16 bf16_t;
typedef __bf16 bf16x8 __attribute__((ext_vector_type(8)));
typedef __bf16 bf16x4 __attribute__((ext_vector_type(4)));
typedef float f32x4 __attribute__((ext_vector_type(4)));

#define MFMA16(A, B, C) __builtin_amdgcn_mfma_f32_16x16x32_bf16(A, B, C, 0, 0, 0)

#if __has_builtin(__builtin_amdgcn_exp2f)
#define EXP2F(x) __builtin_amdgcn_exp2f(x)
#else
#define EXP2F(x) exp2f(x)
#endif

#define GLOAD_LDS16(g, l)                                                   \
  __builtin_amdgcn_global_load_lds(                                         \
      (const __attribute__((address_space(1))) void*)(g),                   \
      (__attribute__((address_space(3))) void*)(l), 16, 0, 0)

// Problem: Z=2, N=2048, DM=1024, H=16, DK=64
#define SL2E 0.18033688011112042f  // 0.125 * log2(e)
#define VT_STRIDE 131072           // 64*2048

// ---------------- K0: convert / repack ----------------
__global__ __launch_bounds__(256) void convert_kernel(
    const float* __restrict__ x, const float* __restrict__ qw, const float* __restrict__ kw,
    const float* __restrict__ vw, const float* __restrict__ qb, const float* __restrict__ kb,
    const float* __restrict__ vb, const float* __restrict__ ow,
    bf16_t* __restrict__ xb, bf16_t* __restrict__ wqkv, bf16_t* __restrict__ wo,
    float* __restrict__ bias)
{
  const int bid = blockIdx.x, tid = threadIdx.x;
  if (bid < 768) {
    // tile: (sec,h) = bid/16, d0 = (bid%16)*64 ; transpose w[h][d][k] -> wqkv[(sec*1024+h*64+k)][d]
    __shared__ float tile[64][65];
    int sh = bid >> 4, db = bid & 15;
    int sec = sh >> 4, h = sh & 15;
    int d0 = db * 64;
    const float* w = sec == 0 ? qw : (sec == 1 ? kw : vw);  // [H][DM][DK]
    int dd = tid >> 2, kk0 = (tid & 3) * 16;
    const float* src = &w[((int64_t)h * 1024 + d0 + dd) * 64 + kk0];
#pragma unroll
    for (int j = 0; j < 4; j++) {
      float4 v = *(const float4*)&src[j * 4];
      tile[dd][kk0 + j * 4 + 0] = v.x;
      tile[dd][kk0 + j * 4 + 1] = v.y;
      tile[dd][kk0 + j * 4 + 2] = v.z;
      tile[dd][kk0 + j * 4 + 3] = v.w;
    }
    __syncthreads();
    int kk = tid >> 2, dd0 = (tid & 3) * 16;
    bf16x8 o0, o1;
#pragma unroll
    for (int j = 0; j < 8; j++) o0[j] = (bf16_t)tile[dd0 + j][kk];
#pragma unroll
    for (int j = 0; j < 8; j++) o1[j] = (bf16_t)tile[dd0 + 8 + j][kk];
    bf16_t* dst = &wqkv[(int64_t)(sh * 64 + kk) * 1024 + d0 + dd0];
    *(bf16x8*)dst = o0;
    *(bf16x8*)(dst + 8) = o1;
  } else if (bid < 2816) {
    int64_t base = ((int64_t)(bid - 768) * 256 + tid) * 8;
    float4 a = *(const float4*)&x[base];
    float4 b = *(const float4*)&x[base + 4];
    bf16x8 o = {(bf16_t)a.x, (bf16_t)a.y, (bf16_t)a.z, (bf16_t)a.w,
                (bf16_t)b.x, (bf16_t)b.y, (bf16_t)b.z, (bf16_t)b.w};
    *(bf16x8*)&xb[base] = o;
  } else if (bid < 3328) {
    int64_t base = ((int64_t)(bid - 2816) * 256 + tid) * 8;
    float4 a = *(const float4*)&ow[base];
    float4 b = *(const float4*)&ow[base + 4];
    bf16x8 o = {(bf16_t)a.x, (bf16_t)a.y, (bf16_t)a.z, (bf16_t)a.w,
                (bf16_t)b.x, (bf16_t)b.y, (bf16_t)b.z, (bf16_t)b.w};
    *(bf16x8*)&wo[base] = o;
  } else {
    for (int j = tid; j < 3072; j += 256) {
      int sec = j >> 10, c = j & 1023;
      const float* b = sec == 0 ? qb : (sec == 1 ? kb : vb);
      bias[j] = b[c];
    }
  }
}

// ---------------- GEMM (pipelined): C[M x Ndim] = A * Bt^T, K=1024, M=4096 ----------
// TM x 128 tile, BK=64, 256 thr / 4 waves (2x2). Double-buffered LDS. Per iter:
//   s_waitcnt lgkmcnt(0) + s_barrier   (drain this wave's ds_reads of buf[next];
//                                       bare s_barrier does NOT wait lgkm)
//   stage(next) -> s_waitcnt vmcnt(MT+4) -> s_barrier -> compute(cur)
// No vmcnt(0) drain except the tail — prefetch crosses both barriers.
template <int MODE, int TM>
__global__ __launch_bounds__(256) void gemm_kernel(
    const bf16_t* __restrict__ A, const bf16_t* __restrict__ Bt, const float* __restrict__ bias,
    bf16_t* __restrict__ qout, bf16_t* __restrict__ kout, bf16_t* __restrict__ vtout,
    float* __restrict__ fout, int Ndim)
{
  const int Kdim = 1024;
  const int MT = TM / 32;                  // m-tiles per wave
  const int AS_SZ = TM * 64, BS_SZ = 128 * 64, BUF = AS_SZ + BS_SZ;
  __shared__ bf16_t smem[2 * (TM * 64 + 128 * 64)];

  const int tid = threadIdx.x;
  const int wave = tid >> 6, lane = tid & 63;
  const int l15 = lane & 15, quad = lane >> 4;
  const int wr = wave >> 1, wc = wave & 1;  // wave quadrant (rows TM/2, cols 64)

  // XCD-aware swizzle: same-bm blocks on same XCD (A panel fits 4MB L2)
  const int MB = 4096 / TM;                // grid rows
  const int GPX = MB / 8;
  const int xcd = blockIdx.x & 7, j = blockIdx.x >> 3;
  const int bm = (xcd * GPX + (j % GPX)) * TM;
  const int bn = (j / GPX) * 128;

  f32x4 acc[MT][4] = {};

  const int lr = lane >> 3;                // staging: lane covers row +lr, col 8*(lane&7)
  const int lc = (lane & 7) * 8;

  auto stage = [&](int b, int kk) {
    bf16_t* as = smem + b * BUF;
    bf16_t* bs = as + AS_SZ;
#pragma unroll
    for (int jj = 0; jj < MT; jj++) {      // A: TM x 64
      int r = wave * (TM / 4) + jj * 8;
      GLOAD_LDS16(A + (int64_t)(bm + r + lr) * Kdim + kk + lc, &as[r * 64]);
    }
#pragma unroll
    for (int jj = 0; jj < 4; jj++) {       // B: 128 x 64
      int r = wave * 32 + jj * 8;
      GLOAD_LDS16(Bt + (int64_t)(bn + r + lr) * Kdim + kk + lc, &bs[r * 64]);
    }
  };

  stage(0, 0);
  for (int it = 0; it < 16; ++it) {
    int cur = it & 1;
    if (it < 15) {
      // drain this wave's pending LDS reads of buf[next], THEN sync, THEN overwrite
      asm volatile("s_waitcnt lgkmcnt(0)\n\ts_barrier" ::: "memory");
      stage(cur ^ 1, (it + 1) * 64);
      asm volatile("s_waitcnt vmcnt(%0)" ::"i"(MT + 4) : "memory");  // own cur loads landed
    } else {
      asm volatile("s_waitcnt vmcnt(0)" ::: "memory");
    }
    asm volatile("s_barrier" ::: "memory");    // all waves' cur loads landed
    const bf16_t* as = smem + cur * BUF;
    const bf16_t* bs = as + AS_SZ;
#pragma unroll
    for (int kc = 0; kc < 2; kc++) {
      bf16x8 af[MT], bfr[4];
#pragma unroll
      for (int mt = 0; mt < MT; mt++)
        af[mt] = *(const bf16x8*)&as[(wr * (TM / 2) + mt * 16 + l15) * 64 + kc * 32 + quad * 8];
#pragma unroll
      for (int nt = 0; nt < 4; nt++)
        bfr[nt] = *(const bf16x8*)&bs[(wc * 64 + nt * 16 + l15) * 64 + kc * 32 + quad * 8];
#pragma unroll
      for (int mt = 0; mt < MT; mt++)
#pragma unroll
        for (int nt = 0; nt < 4; nt++) acc[mt][nt] = MFMA16(af[mt], bfr[nt], acc[mt][nt]);
    }
  }

  if (MODE == 0 && bn >= 2048) {
    // V block: transpose through LDS, coalesced Vt store
    __syncthreads();
    bf16_t* Ct = smem;                     // [128 cols][CTS rows]
    const int CTS = 136;                   // 272B stride: 16B-aligned, 2-way-bank only
#pragma unroll
    for (int mt = 0; mt < MT; mt++) {
#pragma unroll
      for (int nt = 0; nt < 4; nt++) {
        int c = wc * 64 + nt * 16 + l15;
        int rw = wr * (TM / 2) + mt * 16 + quad * 4;
        bf16x4 pv;
#pragma unroll
        for (int r = 0; r < 4; r++) pv[r] = (bf16_t)(acc[mt][nt][r] + bias[bn + c]);
        *(bf16x4*)&Ct[c * CTS + rw] = pv;
      }
    }
    __syncthreads();
    int z = bm >> 11, n0 = bm & 2047;
    int colb = tid >> 4, nch = (tid & 15) * 8;
#pragma unroll
    for (int p = 0; p < 8; p++) {
      int c = p * 16 + colb;
      int hk = (bn + c) & 1023;
      int hh = hk >> 6, dk = hk & 63;
      int zh = z * 16 + hh;
      bf16x8 vv = *(const bf16x8*)&Ct[c * CTS + nch];
      *(bf16x8*)&vtout[(int64_t)zh * VT_STRIDE + dk * 2048 + n0 + nch] = vv;
    }
    return;
  }

#pragma unroll
  for (int mt = 0; mt < MT; mt++) {
#pragma unroll
    for (int nt = 0; nt < 4; nt++) {
#pragma unroll
      for (int r = 0; r < 4; r++) {
        int row = bm + wr * (TM / 2) + mt * 16 + quad * 4 + r;  // = z*2048 + n
        int col = bn + wc * 64 + nt * 16 + l15;
        float v = acc[mt][nt][r];
        if (MODE == 0) {
          v += bias[col];
          int sec = col >> 10, hk = col & 1023;
          int hh = hk >> 6, dk = hk & 63;
          int z = row >> 11, n = row & 2047;
          int zh = z * 16 + hh;
          if (sec == 0) {
            qout[(((int64_t)zh * 2048 + n) << 6) + dk] = (bf16_t)(v * SL2E);
          } else {
            kout[(((int64_t)zh * 2048 + n) << 6) + dk] = (bf16_t)v;
          }
        } else {
          fout[(int64_t)row * Ndim + col] = v;
        }
      }
    }
  }
}

// ---------------- K2: flash attention (S^T, direct-global K/V frags, no inner barriers) ----
// block = 256 thr (4 waves), one (zh, 128-row q-tile); wave w owns q-rows [32w,32w+32)
// as 2 strips of 16. S^T = K·Q^T (C col = q-row, one per lane). K A-frags and V B-frags
// are loaded DIRECTLY from global (K [key][dk], Vt [dk][key] match fragment layouts;
// 64B-contiguous per 16-lane group; tiles fit L1 so the 4-wave re-read hits cache).
// LDS holds only the P C->A round-trip (per-wave private) and Mkf. No barriers in the
// K-loop; 26KB LDS -> ~4 blocks/CU to hide the direct-load latency.
__global__ __launch_bounds__(256, 4) void attn_kernel(
    const bf16_t* __restrict__ Q, const bf16_t* __restrict__ K, const bf16_t* __restrict__ Vt,
    const int* __restrict__ mask, bf16_t* __restrict__ ctx)
{
  __shared__ float Mkf[2048];         // 0 or -1e30 per key
  __shared__ bf16_t Ps[4][32 * 72];   // per-wave private, 2 strips

  const int tid = threadIdx.x;
  const int wave = tid >> 6, lane = tid & 63;
  const int l15 = lane & 15, quad = lane >> 4;
  const int bid = blockIdx.x;
  const int qt = bid & 15, zh = bid >> 4;
  const int z = zh >> 4, h = zh & 15;

  const bf16_t* Qb = Q + ((int64_t)zh * 2048 + qt * 128) * 64;
  const bf16_t* Kb = K + (int64_t)zh * 2048 * 64;
  const bf16_t* Vb = Vt + (int64_t)zh * VT_STRIDE;
  bf16_t* Psw = Ps[wave];

  // Q fragments (B-operand), strip s rows = wave*32 + s*16 + l15
  bf16x8 qf[2][2];
#pragma unroll
  for (int s = 0; s < 2; s++) {
    qf[s][0] = *(const bf16x8*)&Qb[(wave * 32 + s * 16 + l15) * 64 + quad * 8];
    qf[s][1] = *(const bf16x8*)&Qb[(wave * 32 + s * 16 + l15) * 64 + 32 + quad * 8];
  }

  {
    const int4* mp = (const int4*)(mask + z * 2048);
    for (int i = tid; i < 512; i += 256) {
      int4 m4 = mp[i];
      float4 f;
      f.x = m4.x ? 0.f : -1e30f;
      f.y = m4.y ? 0.f : -1e30f;
      f.z = m4.z ? 0.f : -1e30f;
      f.w = m4.w ? 0.f : -1e30f;
      *(float4*)&Mkf[i * 4] = f;
    }
  }
  __syncthreads();

  float l_run[2] = {0.f, 0.f};
  f32x4 o[2][4] = {};

  for (int kt = 0; kt < 32; kt++) {
    const bf16_t* Kt = Kb + (int64_t)kt * 64 * 64;

    // K A-frags + mask-init, direct from global / LDS
    f32x4 minit[4];
    bf16x8 kf0[4], kf1[4];
#pragma unroll
    for (int mb = 0; mb < 4; mb++) {
      minit[mb] = *(const f32x4*)&Mkf[kt * 64 + mb * 16 + quad * 4];
      kf0[mb] = *(const bf16x8*)&Kt[(mb * 16 + l15) * 64 + quad * 8];
      kf1[mb] = *(const bf16x8*)&Kt[(mb * 16 + l15) * 64 + 32 + quad * 8];
    }

    // S^T + exp2 + P-write for both strips
#pragma unroll
    for (int s = 0; s < 2; s++) {
      float rs = 0.f;
#pragma unroll
      for (int mb = 0; mb < 4; mb++) {
        f32x4 t = minit[mb];
        t = MFMA16(kf0[mb], qf[s][0], t);
        t = MFMA16(kf1[mb], qf[s][1], t);
        bf16x4 pk;
#pragma unroll
        for (int r = 0; r < 4; r++) {
          float p = EXP2F(t[r]);
          rs += p;
          pk[r] = (bf16_t)p;
        }
        *(bf16x4*)&Psw[(s * 16 + l15) * 72 + mb * 16 + quad * 4] = pk;
      }
      l_run[s] += rs;   // cross-quad reduction deferred to epilogue
    }

    // P A-fragments (same wave wrote them; in-wave LDS ordering suffices)
    bf16x8 p0[2], p1[2];
#pragma unroll
    for (int s = 0; s < 2; s++) {
      p0[s] = *(const bf16x8*)&Psw[(s * 16 + l15) * 72 + quad * 8];
      p1[s] = *(const bf16x8*)&Psw[(s * 16 + l15) * 72 + 32 + quad * 8];
    }

    // PV: V B-frags direct from global, read once, serve both strips
#pragma unroll
    for (int nb = 0; nb < 4; nb++) {
      const bf16_t* Vr = Vb + (int64_t)(nb * 16 + l15) * 2048 + kt * 64;
      bf16x8 v0 = *(const bf16x8*)&Vr[quad * 8];
      bf16x8 v1 = *(const bf16x8*)&Vr[32 + quad * 8];
#pragma unroll
      for (int s = 0; s < 2; s++) {
        o[s][nb] = MFMA16(p0[s], v0, o[s][nb]);
        o[s][nb] = MFMA16(p1[s], v1, o[s][nb]);
      }
    }
  }

  // epilogue: finish l reduction, apply query mask + 1/l, store ctx
#pragma unroll
  for (int s = 0; s < 2; s++) {
    float l = l_run[s];
    l += __shfl_xor(l, 16);
    l += __shfl_xor(l, 32);
    float inv4[4];
#pragma unroll
    for (int r = 0; r < 4; r++) {
      int qrow = qt * 128 + wave * 32 + s * 16 + quad * 4 + r;
      float lv = __shfl(l, quad * 4 + r);
      int valid = mask[z * 2048 + qrow];
      inv4[r] = (valid && lv > 0.f) ? 1.0f / lv : 0.f;
    }
#pragma unroll
    for (int nb = 0; nb < 4; nb++) {
#pragma unroll
      for (int r = 0; r < 4; r++) {
        int qrow = qt * 128 + wave * 32 + s * 16 + quad * 4 + r;
        ctx[((int64_t)(z * 2048 + qrow)) * 1024 + h * 64 + nb * 16 + l15] =
            (bf16_t)(o[s][nb][r] * inv4[r]);
      }
    }
  }
}

extern "C" void kernel_launch(void* const* d_in, const int* in_sizes, int n_in,
                              void* d_out, int out_size, void* d_ws, size_t ws_size,
                              hipStream_t stream)
{
  (void)in_sizes; (void)n_in; (void)out_size; (void)ws_size;
  const float* x  = (const float*)d_in[0];
  const int* mask = (const int*)d_in[1];
  const float* qw = (const float*)d_in[2];
  const float* kw = (const float*)d_in[3];
  const float* vw = (const float*)d_in[4];
  const float* qb = (const float*)d_in[5];
  const float* kb = (const float*)d_in[6];
  const float* vb = (const float*)d_in[7];
  const float* ow = (const float*)d_in[8];
  float* out = (float*)d_out;

  bf16_t* xb   = (bf16_t*)d_ws;
  bf16_t* wqkv = xb + 4194304;
  bf16_t* wo   = wqkv + 3145728;
  float*  bias = (float*)(wo + 1048576);
  bf16_t* Qb   = (bf16_t*)(bias + 3072);
  bf16_t* Kb   = Qb + 4194304;
  bf16_t* Vtb  = Kb + 4194304;
  bf16_t* ctx  = Vtb + (int64_t)32 * VT_STRIDE;

  convert_kernel<<<3329, 256, 0, stream>>>(x, qw, kw, vw, qb, kb, vb, ow,
                                           xb, wqkv, wo, bias);
  gemm_kernel<0, 128><<<(4096 / 128) * (3072 / 128), 256, 0, stream>>>(
      xb, wqkv, bias, Qb, Kb, Vtb, nullptr, 3072);
  attn_kernel<<<2 * 16 * 16, 256, 0, stream>>>(Qb, Kb, Vtb, mask, ctx);
  gemm_kernel<1, 64><<<(4096 / 64) * (1024 / 128), 256, 0, stream>>>(
      ctx, wo, nullptr, nullptr, nullptr, nullptr, out, 1024);
}

// Round 10
// 197.775 us; speedup vs baseline: 1.4612x; 1.4612x over previous
//
#include <hip/hip_runtime.h>
#include <stdint.h>

typedef __bf16 bf16_t;
typedef __bf16 bf16x8 __attribute__((ext_vector_type(8)));
typedef __bf16 bf16x4 __attribute__((ext_vector_type(4)));
typedef float f32x4 __attribute__((ext_vector_type(4)));

#define MFMA16(A, B, C) __builtin_amdgcn_mfma_f32_16x16x32_bf16(A, B, C, 0, 0, 0)

#if __has_builtin(__builtin_amdgcn_exp2f)
#define EXP2F(x) __builtin_amdgcn_exp2f(x)
#else
#define EXP2F(x) exp2f(x)
#endif

#define GLOAD_LDS16(g, l)                                                   \
  __builtin_amdgcn_global_load_lds(                                         \
      (const __attribute__((address_space(1))) void*)(g),                   \
      (__attribute__((address_space(3))) void*)(l), 16, 0, 0)

// Problem: Z=2, N=2048, DM=1024, H=16, DK=64
#define SL2E 0.18033688011112042f  // 0.125 * log2(e)
#define VT_STRIDE 131072           // 64*2048

// ---------------- K0: convert / repack ----------------
__global__ __launch_bounds__(256) void convert_kernel(
    const float* __restrict__ x, const float* __restrict__ qw, const float* __restrict__ kw,
    const float* __restrict__ vw, const float* __restrict__ qb, const float* __restrict__ kb,
    const float* __restrict__ vb, const float* __restrict__ ow,
    bf16_t* __restrict__ xb, bf16_t* __restrict__ wqkv, bf16_t* __restrict__ wo,
    float* __restrict__ bias)
{
  const int bid = blockIdx.x, tid = threadIdx.x;
  if (bid < 768) {
    // tile: (sec,h) = bid/16, d0 = (bid%16)*64 ; transpose w[h][d][k] -> wqkv[(sec*1024+h*64+k)][d]
    __shared__ float tile[64][65];
    int sh = bid >> 4, db = bid & 15;
    int sec = sh >> 4, h = sh & 15;
    int d0 = db * 64;
    const float* w = sec == 0 ? qw : (sec == 1 ? kw : vw);  // [H][DM][DK]
    int dd = tid >> 2, kk0 = (tid & 3) * 16;
    const float* src = &w[((int64_t)h * 1024 + d0 + dd) * 64 + kk0];
#pragma unroll
    for (int j = 0; j < 4; j++) {
      float4 v = *(const float4*)&src[j * 4];
      tile[dd][kk0 + j * 4 + 0] = v.x;
      tile[dd][kk0 + j * 4 + 1] = v.y;
      tile[dd][kk0 + j * 4 + 2] = v.z;
      tile[dd][kk0 + j * 4 + 3] = v.w;
    }
    __syncthreads();
    int kk = tid >> 2, dd0 = (tid & 3) * 16;
    bf16x8 o0, o1;
#pragma unroll
    for (int j = 0; j < 8; j++) o0[j] = (bf16_t)tile[dd0 + j][kk];
#pragma unroll
    for (int j = 0; j < 8; j++) o1[j] = (bf16_t)tile[dd0 + 8 + j][kk];
    bf16_t* dst = &wqkv[(int64_t)(sh * 64 + kk) * 1024 + d0 + dd0];
    *(bf16x8*)dst = o0;
    *(bf16x8*)(dst + 8) = o1;
  } else if (bid < 2816) {
    int64_t base = ((int64_t)(bid - 768) * 256 + tid) * 8;
    float4 a = *(const float4*)&x[base];
    float4 b = *(const float4*)&x[base + 4];
    bf16x8 o = {(bf16_t)a.x, (bf16_t)a.y, (bf16_t)a.z, (bf16_t)a.w,
                (bf16_t)b.x, (bf16_t)b.y, (bf16_t)b.z, (bf16_t)b.w};
    *(bf16x8*)&xb[base] = o;
  } else if (bid < 3328) {
    int64_t base = ((int64_t)(bid - 2816) * 256 + tid) * 8;
    float4 a = *(const float4*)&ow[base];
    float4 b = *(const float4*)&ow[base + 4];
    bf16x8 o = {(bf16_t)a.x, (bf16_t)a.y, (bf16_t)a.z, (bf16_t)a.w,
                (bf16_t)b.x, (bf16_t)b.y, (bf16_t)b.z, (bf16_t)b.w};
    *(bf16x8*)&wo[base] = o;
  } else {
    for (int j = tid; j < 3072; j += 256) {
      int sec = j >> 10, c = j & 1023;
      const float* b = sec == 0 ? qb : (sec == 1 ? kb : vb);
      bias[j] = b[c];
    }
  }
}

// ---------------- GEMM (pipelined): C[M x Ndim] = A * Bt^T, K=1024, M=4096 ----------
// TM x 128 tile, BK=64, 256 thr / 4 waves (2x2). Double-buffered LDS. Per iter:
//   s_waitcnt lgkmcnt(0) + s_barrier   (drain this wave's ds_reads of buf[next];
//                                       bare s_barrier does NOT wait lgkm)
//   stage(next) -> s_waitcnt vmcnt(MT+4) -> s_barrier -> compute(cur)
// No vmcnt(0) drain except the tail — prefetch crosses both barriers.
template <int MODE, int TM>
__global__ __launch_bounds__(256) void gemm_kernel(
    const bf16_t* __restrict__ A, const bf16_t* __restrict__ Bt, const float* __restrict__ bias,
    bf16_t* __restrict__ qout, bf16_t* __restrict__ kout, bf16_t* __restrict__ vtout,
    float* __restrict__ fout, int Ndim)
{
  const int Kdim = 1024;
  const int MT = TM / 32;                  // m-tiles per wave
  const int AS_SZ = TM * 64, BS_SZ = 128 * 64, BUF = AS_SZ + BS_SZ;
  __shared__ bf16_t smem[2 * (TM * 64 + 128 * 64)];

  const int tid = threadIdx.x;
  const int wave = tid >> 6, lane = tid & 63;
  const int l15 = lane & 15, quad = lane >> 4;
  const int wr = wave >> 1, wc = wave & 1;  // wave quadrant (rows TM/2, cols 64)

  // XCD-aware swizzle: same-bm blocks on same XCD (A panel fits 4MB L2)
  const int MB = 4096 / TM;                // grid rows
  const int GPX = MB / 8;
  const int xcd = blockIdx.x & 7, j = blockIdx.x >> 3;
  const int bm = (xcd * GPX + (j % GPX)) * TM;
  const int bn = (j / GPX) * 128;

  f32x4 acc[MT][4] = {};

  const int lr = lane >> 3;                // staging: lane covers row +lr, col 8*(lane&7)
  const int lc = (lane & 7) * 8;

  auto stage = [&](int b, int kk) {
    bf16_t* as = smem + b * BUF;
    bf16_t* bs = as + AS_SZ;
#pragma unroll
    for (int jj = 0; jj < MT; jj++) {      // A: TM x 64
      int r = wave * (TM / 4) + jj * 8;
      GLOAD_LDS16(A + (int64_t)(bm + r + lr) * Kdim + kk + lc, &as[r * 64]);
    }
#pragma unroll
    for (int jj = 0; jj < 4; jj++) {       // B: 128 x 64
      int r = wave * 32 + jj * 8;
      GLOAD_LDS16(Bt + (int64_t)(bn + r + lr) * Kdim + kk + lc, &bs[r * 64]);
    }
  };

  stage(0, 0);
  for (int it = 0; it < 16; ++it) {
    int cur = it & 1;
    if (it < 15) {
      // drain this wave's pending LDS reads of buf[next], THEN sync, THEN overwrite
      asm volatile("s_waitcnt lgkmcnt(0)\n\ts_barrier" ::: "memory");
      stage(cur ^ 1, (it + 1) * 64);
      asm volatile("s_waitcnt vmcnt(%0)" ::"i"(MT + 4) : "memory");  // own cur loads landed
    } else {
      asm volatile("s_waitcnt vmcnt(0)" ::: "memory");
    }
    asm volatile("s_barrier" ::: "memory");    // all waves' cur loads landed
    const bf16_t* as = smem + cur * BUF;
    const bf16_t* bs = as + AS_SZ;
#pragma unroll
    for (int kc = 0; kc < 2; kc++) {
      bf16x8 af[MT], bfr[4];
#pragma unroll
      for (int mt = 0; mt < MT; mt++)
        af[mt] = *(const bf16x8*)&as[(wr * (TM / 2) + mt * 16 + l15) * 64 + kc * 32 + quad * 8];
#pragma unroll
      for (int nt = 0; nt < 4; nt++)
        bfr[nt] = *(const bf16x8*)&bs[(wc * 64 + nt * 16 + l15) * 64 + kc * 32 + quad * 8];
#pragma unroll
      for (int mt = 0; mt < MT; mt++)
#pragma unroll
        for (int nt = 0; nt < 4; nt++) acc[mt][nt] = MFMA16(af[mt], bfr[nt], acc[mt][nt]);
    }
  }

  if (MODE == 0 && bn >= 2048) {
    // V block: transpose through LDS, coalesced Vt store
    __syncthreads();
    bf16_t* Ct = smem;                     // [128 cols][CTS rows]
    const int CTS = 136;                   // 272B stride: 16B-aligned, 2-way-bank only
#pragma unroll
    for (int mt = 0; mt < MT; mt++) {
#pragma unroll
      for (int nt = 0; nt < 4; nt++) {
        int c = wc * 64 + nt * 16 + l15;
        int rw = wr * (TM / 2) + mt * 16 + quad * 4;
        bf16x4 pv;
#pragma unroll
        for (int r = 0; r < 4; r++) pv[r] = (bf16_t)(acc[mt][nt][r] + bias[bn + c]);
        *(bf16x4*)&Ct[c * CTS + rw] = pv;
      }
    }
    __syncthreads();
    int z = bm >> 11, n0 = bm & 2047;
    int colb = tid >> 4, nch = (tid & 15) * 8;
#pragma unroll
    for (int p = 0; p < 8; p++) {
      int c = p * 16 + colb;
      int hk = (bn + c) & 1023;
      int hh = hk >> 6, dk = hk & 63;
      int zh = z * 16 + hh;
      bf16x8 vv = *(const bf16x8*)&Ct[c * CTS + nch];
      *(bf16x8*)&vtout[(int64_t)zh * VT_STRIDE + dk * 2048 + n0 + nch] = vv;
    }
    return;
  }

#pragma unroll
  for (int mt = 0; mt < MT; mt++) {
#pragma unroll
    for (int nt = 0; nt < 4; nt++) {
#pragma unroll
      for (int r = 0; r < 4; r++) {
        int row = bm + wr * (TM / 2) + mt * 16 + quad * 4 + r;  // = z*2048 + n
        int col = bn + wc * 64 + nt * 16 + l15;
        float v = acc[mt][nt][r];
        if (MODE == 0) {
          v += bias[col];
          int sec = col >> 10, hk = col & 1023;
          int hh = hk >> 6, dk = hk & 63;
          int z = row >> 11, n = row & 2047;
          int zh = z * 16 + hh;
          if (sec == 0) {
            qout[(((int64_t)zh * 2048 + n) << 6) + dk] = (bf16_t)(v * SL2E);
          } else {
            kout[(((int64_t)zh * 2048 + n) << 6) + dk] = (bf16_t)v;
          }
        } else {
          fout[(int64_t)row * Ndim + col] = v;
        }
      }
    }
  }
}

// ---------------- K2: flash attention (S^T, DMA-staged swizzled LDS, pipelined) ----
// block = 256 thr (4 waves), one (zh, 128-row q-tile); wave w owns q-rows [32w,32w+32)
// as 2 strips of 16. S^T = K·Q^T (C col = q-row, one per lane).
// K/V tiles staged via global_load_lds into UNPADDED stride-64 LDS with an XOR
// col-block swizzle (lane fetches global col-block (lane&7)^(lane>>3); reader uses
// (q ^ (l15&7))) — conflict-free reads without padding, no wave-issued staging writes.
// Two-barrier pipelined K-loop (lgkmcnt(0)+barrier -> stage(next) -> vmcnt(4) ->
// barrier -> compute): prefetch DMA stays in flight across barriers, no vmcnt(0) drain.
// Mask folded into S accumulator init (-1e30 -> exp2=0); l = register row-sum of P.
__global__ __launch_bounds__(256, 2) void attn_kernel(
    const bf16_t* __restrict__ Q, const bf16_t* __restrict__ K, const bf16_t* __restrict__ Vt,
    const int* __restrict__ mask, bf16_t* __restrict__ ctx)
{
  __shared__ bf16_t Ks[2][64 * 64];      // [key][dk], xor-swizzled cols
  __shared__ bf16_t Vs[2][64 * 64];      // [dk][key], xor-swizzled cols
  __shared__ float Mkf[2048];            // 0 or -1e30 per key
  __shared__ bf16_t Ps[4][2][16 * 72];   // per-wave, per-strip P round-trip

  const int tid = threadIdx.x;
  const int wave = tid >> 6, lane = tid & 63;
  const int l15 = lane & 15, quad = lane >> 4;
  const int bid = blockIdx.x;
  const int qt = bid & 15, zh = bid >> 4;
  const int z = zh >> 4, h = zh & 15;

  const bf16_t* Qb = Q + ((int64_t)zh * 2048 + qt * 128) * 64;
  const bf16_t* Kb = K + (int64_t)zh * 2048 * 64;
  const bf16_t* Vb = Vt + (int64_t)zh * VT_STRIDE;

  // Q fragments (B-operand), strip s rows = wave*32 + s*16 + l15
  bf16x8 qf[2][2];
#pragma unroll
  for (int s = 0; s < 2; s++) {
    qf[s][0] = *(const bf16x8*)&Qb[(wave * 32 + s * 16 + l15) * 64 + quad * 8];
    qf[s][1] = *(const bf16x8*)&Qb[(wave * 32 + s * 16 + l15) * 64 + 32 + quad * 8];
  }

  // mask -> Mkf (f32 additive init); published by the loop's first lgkm-drained barrier
  {
    const int4* mp = (const int4*)(mask + z * 2048);
    for (int i = tid; i < 512; i += 256) {
      int4 m4 = mp[i];
      float4 f;
      f.x = m4.x ? 0.f : -1e30f;
      f.y = m4.y ? 0.f : -1e30f;
      f.z = m4.z ? 0.f : -1e30f;
      f.w = m4.w ? 0.f : -1e30f;
      *(float4*)&Mkf[i * 4] = f;
    }
  }

  // DMA staging: wave w covers K rows [16w,16w+16) and V rows [16w,16w+16), 2 chunks
  // of 8 rows each. Lane lands at lds base + lane*16B = row (+lane>>3), slot lane&7;
  // it fetches global col-block (lane&7) ^ (lane>>3)  (xor swizzle).
  const int slr = lane >> 3;            // 0..7
  const int scb = (lane & 7) ^ slr;     // swizzled global col-block
  auto stage = [&](int b, int kt2) {
#pragma unroll
    for (int c = 0; c < 2; c++) {
      int row = wave * 16 + c * 8;
      GLOAD_LDS16(Kb + (int64_t)(kt2 * 64 + row + slr) * 64 + scb * 8, &Ks[b][row * 64]);
      GLOAD_LDS16(Vb + (int64_t)(row + slr) * 2048 + kt2 * 64 + scb * 8, &Vs[b][row * 64]);
    }
  };

  stage(0, 0);

  float l_run[2] = {0.f, 0.f};
  f32x4 o[2][4] = {};
  const int sw = l15 & 7;               // reader swizzle key

  for (int kt = 0; kt < 32; kt++) {
    int cur = kt & 1;
    // drain own LDS reads of buf[next] (prev iter), then sync, then overwrite
    asm volatile("s_waitcnt lgkmcnt(0)\n\ts_barrier" ::: "memory");
    if (kt < 31) {
      stage(cur ^ 1, kt + 1);
      asm volatile("s_waitcnt vmcnt(4)" ::: "memory");  // own cur-tile DMAs landed
    } else {
      asm volatile("s_waitcnt vmcnt(0)" ::: "memory");
    }
    asm volatile("s_barrier" ::: "memory");             // all waves' cur DMAs landed

    // hoisted fragments: mask-init + K + V (shared across both strips)
    f32x4 minit[4];
    bf16x8 kf0[4], kf1[4], vf0[4], vf1[4];
#pragma unroll
    for (int mb = 0; mb < 4; mb++) {
      minit[mb] = *(const f32x4*)&Mkf[kt * 64 + mb * 16 + quad * 4];
      kf0[mb] = *(const bf16x8*)&Ks[cur][(mb * 16 + l15) * 64 + ((quad ^ sw) * 8)];
      kf1[mb] = *(const bf16x8*)&Ks[cur][(mb * 16 + l15) * 64 + (((quad + 4) ^ sw) * 8)];
      vf0[mb] = *(const bf16x8*)&Vs[cur][(mb * 16 + l15) * 64 + ((quad ^ sw) * 8)];
      vf1[mb] = *(const bf16x8*)&Vs[cur][(mb * 16 + l15) * 64 + (((quad + 4) ^ sw) * 8)];
    }

#pragma unroll
    for (int s = 0; s < 2; s++) {
      bf16_t* Psw = Ps[wave][s];
      float rs = 0.f;
#pragma unroll
      for (int mb = 0; mb < 4; mb++) {
        f32x4 t = minit[mb];
        t = MFMA16(kf0[mb], qf[s][0], t);
        t = MFMA16(kf1[mb], qf[s][1], t);
        bf16x4 pk;
#pragma unroll
        for (int r = 0; r < 4; r++) {
          float p = EXP2F(t[r]);
          rs += p;
          pk[r] = (bf16_t)p;
        }
        *(bf16x4*)&Psw[l15 * 72 + mb * 16 + quad * 4] = pk;
      }
      l_run[s] += rs;   // cross-quad reduction deferred to epilogue

      // P A-fragments (same wave wrote them; per-wave DS ops are in-order)
      bf16x8 p0 = *(const bf16x8*)&Psw[l15 * 72 + quad * 8];
      bf16x8 p1 = *(const bf16x8*)&Psw[l15 * 72 + 32 + quad * 8];
#pragma unroll
      for (int nb = 0; nb < 4; nb++) {
        o[s][nb] = MFMA16(p0, vf0[nb], o[s][nb]);
        o[s][nb] = MFMA16(p1, vf1[nb], o[s][nb]);
      }
    }
  }

  // epilogue: finish l reduction, apply query mask + 1/l, store ctx
#pragma unroll
  for (int s = 0; s < 2; s++) {
    float l = l_run[s];
    l += __shfl_xor(l, 16);
    l += __shfl_xor(l, 32);
    float inv4[4];
#pragma unroll
    for (int r = 0; r < 4; r++) {
      int qrow = qt * 128 + wave * 32 + s * 16 + quad * 4 + r;
      float lv = __shfl(l, quad * 4 + r);
      int valid = mask[z * 2048 + qrow];
      inv4[r] = (valid && lv > 0.f) ? 1.0f / lv : 0.f;
    }
#pragma unroll
    for (int nb = 0; nb < 4; nb++) {
#pragma unroll
      for (int r = 0; r < 4; r++) {
        int qrow = qt * 128 + wave * 32 + s * 16 + quad * 4 + r;
        ctx[((int64_t)(z * 2048 + qrow)) * 1024 + h * 64 + nb * 16 + l15] =
            (bf16_t)(o[s][nb][r] * inv4[r]);
      }
    }
  }
}

extern "C" void kernel_launch(void* const* d_in, const int* in_sizes, int n_in,
                              void* d_out, int out_size, void* d_ws, size_t ws_size,
                              hipStream_t stream)
{
  (void)in_sizes; (void)n_in; (void)out_size; (void)ws_size;
  const float* x  = (const float*)d_in[0];
  const int* mask = (const int*)d_in[1];
  const float* qw = (const float*)d_in[2];
  const float* kw = (const float*)d_in[3];
  const float* vw = (const float*)d_in[4];
  const float* qb = (const float*)d_in[5];
  const float* kb = (const float*)d_in[6];
  const float* vb = (const float*)d_in[7];
  const float* ow = (const float*)d_in[8];
  float* out = (float*)d_out;

  bf16_t* xb   = (bf16_t*)d_ws;
  bf16_t* wqkv = xb + 4194304;
  bf16_t* wo   = wqkv + 3145728;
  float*  bias = (float*)(wo + 1048576);
  bf16_t* Qb   = (bf16_t*)(bias + 3072);
  bf16_t* Kb   = Qb + 4194304;
  bf16_t* Vtb  = Kb + 4194304;
  bf16_t* ctx  = Vtb + (int64_t)32 * VT_STRIDE;

  convert_kernel<<<3329, 256, 0, stream>>>(x, qw, kw, vw, qb, kb, vb, ow,
                                           xb, wqkv, wo, bias);
  gemm_kernel<0, 128><<<(4096 / 128) * (3072 / 128), 256, 0, stream>>>(
      xb, wqkv, bias, Qb, Kb, Vtb, nullptr, 3072);
  attn_kernel<<<2 * 16 * 16, 256, 0, stream>>>(Qb, Kb, Vtb, mask, ctx);
  gemm_kernel<1, 64><<<(4096 / 64) * (1024 / 128), 256, 0, stream>>>(
      ctx, wo, nullptr, nullptr, nullptr, nullptr, out, 1024);
}